// Round 17
// baseline (5833.638 us; speedup 1.0000x reference)
//
#include <hip/hip_runtime.h>
#include <hip/hip_bf16.h>

// FP8Linear: out = Xq @ Wq^T + bias. Reference quantize (scale=1) == RNE
// conversion to OCP e4m3fn; x stored as e4m3(x); w stored as e4m3(w*2^6)
// with MFMA B-scale 2^-6 (e8m0 0x79) so all |w|>=2^-12 quantize EXACTLY.
// GEMM R17: counted-vmcnt pipeline at WHOLE-TILE granularity (simple,
// verifiable ledger, unlike the failed 8-phase ports):
//   256x256 tile, BK=64, 1024 thr / 16 waves (4Mx4N, 64x64 out, acc[2][2]),
//   3 x 32KB LDS buffers, 2-tile-deep DMA prefetch (2 instr/tile),
//   per tile: stage(t+2); vmcnt(2) [t+1 landed, t+2 in flight - never 0];
//   raw s_barrier; sched_barrier(0); MFMA IMMEDIATELY (frags pre-read last
//   body - ds_read latency hidden under the barrier wait, m201's property);
//   then read frags(t+1) at body bottom (landed by this body's wait).
// WAR: buffer overwritten by stage(t+3) at body t+2 top; its readers
// finished before barrier t+1 (lgkm before their MFMAs) - >=1 barrier apart.
// 64B-row swizzle FIXED vs R13: q(r)=(r^(r>>2))&3 -> worst case 2-way
// (lanes 16 apart), which is free (m136). Same q on DMA source (both-sides).

typedef int i32x4 __attribute__((ext_vector_type(4)));
typedef int i32x8 __attribute__((ext_vector_type(8)));
typedef float f32x16 __attribute__((ext_vector_type(16)));

#define BM 256
#define BN 256
#define BK 64

// clip to +-448, scale (1 or 64), RNE-encode 8 f32 -> 8 e4m3 bytes.
__global__ __launch_bounds__(256) void quant8(
    const float4* __restrict__ in, int2* __restrict__ out, int n8, float scale) {
    int i = blockIdx.x * blockDim.x + threadIdx.x;
    if (i >= n8) return;
    float4 a = in[i * 2];
    float4 b = in[i * 2 + 1];
    float c0 = fminf(fmaxf(a.x, -448.f), 448.f) * scale;
    float c1 = fminf(fmaxf(a.y, -448.f), 448.f) * scale;
    float c2 = fminf(fmaxf(a.z, -448.f), 448.f) * scale;
    float c3 = fminf(fmaxf(a.w, -448.f), 448.f) * scale;
    float c4 = fminf(fmaxf(b.x, -448.f), 448.f) * scale;
    float c5 = fminf(fmaxf(b.y, -448.f), 448.f) * scale;
    float c6 = fminf(fmaxf(b.z, -448.f), 448.f) * scale;
    float c7 = fminf(fmaxf(b.w, -448.f), 448.f) * scale;
    int lo = __builtin_amdgcn_cvt_pk_fp8_f32(c0, c1, 0, false);
    lo = __builtin_amdgcn_cvt_pk_fp8_f32(c2, c3, lo, true);
    int hi = __builtin_amdgcn_cvt_pk_fp8_f32(c4, c5, 0, false);
    hi = __builtin_amdgcn_cvt_pk_fp8_f32(c6, c7, hi, true);
    out[i] = make_int2(lo, hi);
}

__device__ __forceinline__ void gload_lds16(const void* g, void* l) {
    __builtin_amdgcn_global_load_lds(
        (const __attribute__((address_space(1))) void*)g,
        (__attribute__((address_space(3))) void*)l,
        16, 0, 0);
}

// 64B-row tile, slot swizzle q(r) = (r ^ (r>>2)) & 3.
// LDS[r][slot s] holds logical slot s ^ q(r). Lane reads 32B = slots
// {2*g2, 2*g2+1} of `row`.
__device__ __forceinline__ i32x8 frag64(const unsigned char* base, int row, int g2) {
    const int q = (row ^ (row >> 2)) & 3;
    const unsigned char* p = base + (row << 6);
    i32x4 lo = *(const i32x4*)(p + ((((g2 << 1))     ^ q) << 4));
    i32x4 hi = *(const i32x4*)(p + ((((g2 << 1) | 1) ^ q) << 4));
    i32x8 r;
    r[0] = lo[0]; r[1] = lo[1]; r[2] = lo[2]; r[3] = lo[3];
    r[4] = hi[0]; r[5] = hi[1]; r[6] = hi[2]; r[7] = hi[3];
    return r;
}

// A: Xq8 [M][K] e4m3, B: Wq8 [N][K] e4m3 (pre-scaled by 2^6), C: [M][N] f32
__global__ __launch_bounds__(1024, 1) void gemm_fp8(
    const unsigned char* __restrict__ A, const unsigned char* __restrict__ B,
    const float* __restrict__ bias, float* __restrict__ C,
    int M, int N, int K) {
    // 3 buffers x (A 16KB + B 16KB) = 96 KB
    __shared__ unsigned char lds[98304];

    const int tid = threadIdx.x;
    const int lane = tid & 63;
    const int wave = tid >> 6;   // 0..15
    const int wr = wave >> 2;    // 0..3 -> 64 A-rows each
    const int wc = wave & 3;     // 0..3 -> 64 B-cols each

    // XCD-aware bijective block swizzle (nwg % 8 == 0)
    const int nwg = gridDim.x;
    const int per = nwg >> 3;
    const int bid = blockIdx.x;
    const int wg = (bid & 7) * per + (bid >> 3);
    const int mtiles = M / BM;
    const int bm = wg % mtiles;
    const int bn = wg / mtiles;

    const int arow0 = bm * BM, bcol0 = bn * BN;
    const int NT = K / BK;  // 64

    const int rl = lane & 31;    // fragment row-within-32 (A row / B col)
    const int g2 = lane >> 5;    // k-half selector (32B each)

    const unsigned char* const Ag = A + (size_t)arow0 * K;
    const unsigned char* const Bg = B + (size_t)bcol0 * K;

    // staging: one 16KB unit = 256 rows x 64B; 1024 thr x 16B = 1 instr.
    // thread t -> row t>>2, LDS slot t&3 (linear dest); source col carries
    // the inverse swizzle: logical slot = (t&3) ^ q(row).
    const int srow = tid >> 2;                          // 0..255
    const int sq = (srow ^ (srow >> 2)) & 3;
    const int ssrc = (((tid & 3) ^ sq) << 4);           // byte col in row
    const int sdst = tid * 16;

    auto stage = [&](unsigned char* Lp, int kt) {
        gload_lds16(Ag + (size_t)srow * K + kt + ssrc, Lp + sdst);          // A
        gload_lds16(Bg + (size_t)srow * K + kt + ssrc, Lp + 16384 + sdst);  // B
    };

    f32x16 acc[2][2] = {};

    const int ar0 = wr * 64 + rl, ar1 = wr * 64 + 32 + rl;
    const int br0 = wc * 64 + rl, br1 = wc * 64 + 32 + rl;

    // ---- prologue: stage tiles 0,1; wait tile0; pre-read tile0 frags
    stage(lds, 0);
    stage(lds + 32768, BK);
    asm volatile("s_waitcnt vmcnt(2)");   // tile0's 2 landed; tile1 in flight
    __builtin_amdgcn_s_barrier();
    __builtin_amdgcn_sched_barrier(0);
    i32x8 af0 = frag64(lds, ar0, g2);
    i32x8 af1 = frag64(lds, ar1, g2);
    i32x8 bf0 = frag64(lds + 16384, br0, g2);
    i32x8 bf1 = frag64(lds + 16384, br1, g2);

    for (int t = 0; t < NT; ++t) {
        // earliest possible issue: 2 full tiles of latency cover
        if (t + 2 < NT) stage(lds + ((t + 2) % 3) * 32768, (t + 2) * BK);

        // counted wait: tile t+1 landed (and visible after barrier);
        // tile t+2's 2 loads stay in flight. Never vmcnt(0) mid-loop.
        if (t + 2 < NT) {
            asm volatile("s_waitcnt vmcnt(2)");
        } else {
            asm volatile("s_waitcnt vmcnt(0)");
        }
        __builtin_amdgcn_s_barrier();
        __builtin_amdgcn_sched_barrier(0);  // pin: nothing hoists above barrier

        // MFMAs fire immediately: frags were read LAST body; their ds_read
        // latency was hidden under the barrier wait (m201 property).
        acc[0][0] = __builtin_amdgcn_mfma_scale_f32_32x32x64_f8f6f4(
            af0, bf0, acc[0][0], 0, 0, 0, 0x7F7F7F7F, 0, 0x79797979);
        acc[0][1] = __builtin_amdgcn_mfma_scale_f32_32x32x64_f8f6f4(
            af0, bf1, acc[0][1], 0, 0, 0, 0x7F7F7F7F, 0, 0x79797979);
        acc[1][0] = __builtin_amdgcn_mfma_scale_f32_32x32x64_f8f6f4(
            af1, bf0, acc[1][0], 0, 0, 0, 0x7F7F7F7F, 0, 0x79797979);
        acc[1][1] = __builtin_amdgcn_mfma_scale_f32_32x32x64_f8f6f4(
            af1, bf1, acc[1][1], 0, 0, 0, 0x7F7F7F7F, 0, 0x79797979);

        // pre-read next tile's frags (tile t+1 landed by this body's wait;
        // its buffer is not overwritten until stage(t+4) at body t+2, and
        // all readers pass barrier t+1 only after their lgkm completes).
        if (t + 1 < NT) {
            const unsigned char* Anx = lds + ((t + 1) % 3) * 32768;
            const unsigned char* Bnx = Anx + 16384;
            af0 = frag64(Anx, ar0, g2);
            af1 = frag64(Anx, ar1, g2);
            bf0 = frag64(Bnx, br0, g2);
            bf1 = frag64(Bnx, br1, g2);
        }
    }

    // epilogue: 32x32 C/D: col = lane&31, row = (reg&3)+8*(reg>>2)+4*(lane>>5)
#pragma unroll
    for (int n = 0; n < 2; ++n) {
        int col = bcol0 + wc * 64 + n * 32 + rl;
        float bv = bias[col];
#pragma unroll
        for (int m = 0; m < 2; ++m) {
            int rowb = arow0 + wr * 64 + m * 32 + g2 * 4;
#pragma unroll
            for (int reg = 0; reg < 16; ++reg) {
                int row = rowb + (reg & 3) + 8 * (reg >> 2);
                C[(size_t)row * N + col] = acc[m][n][reg] + bv;
            }
        }
    }
}

extern "C" void kernel_launch(void* const* d_in, const int* in_sizes, int n_in,
                              void* d_out, int out_size, void* d_ws, size_t ws_size,
                              hipStream_t stream) {
    const float* x = (const float*)d_in[0];     // [M,K]
    const float* w = (const float*)d_in[1];     // [N,K]
    const float* bias = (const float*)d_in[2];  // [N]
    float* out = (float*)d_out;

    const int N = in_sizes[2];                 // 16384
    const int K = in_sizes[1] / N;             // 4096
    const int M = in_sizes[0] / K;             // 8192

    unsigned char* xq = (unsigned char*)d_ws;          // M*K = 33.5 MB
    unsigned char* wq = xq + (size_t)M * K;            // N*K = 67 MB

    int nx8 = M * K / 8;
    int nw8 = N * K / 8;
    quant8<<<(nx8 + 255) / 256, 256, 0, stream>>>(
        (const float4*)x, (int2*)xq, nx8, 1.0f);
    quant8<<<(nw8 + 255) / 256, 256, 0, stream>>>(
        (const float4*)w, (int2*)wq, nw8, 64.0f);

    int nwg = (M / BM) * (N / BN);  // 32*64 = 2048, %8==0
    gemm_fp8<<<nwg, 1024, 0, stream>>>(
        xq, wq, bias, out, M, N, K);
}

// Round 18
// 797.773 us; speedup vs baseline: 7.3124x; 7.3124x over previous
//
#include <hip/hip_runtime.h>
#include <hip/hip_bf16.h>

// FP8Linear: out = Xq @ Wq^T + bias. Reference quantize (scale=1) == RNE
// conversion to OCP e4m3fn; x stored as e4m3(x); w stored as e4m3(w*2^6)
// with MFMA B-scale 2^-6 (e8m0 0x79) so all |w|>=2^-12 quantize EXACTLY.
// GEMM R18 = R13's structure (best non-fragile config: dbuf full-tile
// prefetch + 2 blocks/CU + 16 waves/CU, ONE __syncthreads per tile)
// with the swizzle FIXED to R17's hardware-verified zero-conflict form:
// 64B rows, slot swizzle q(r) = (r ^ (r>>2)) & 3 (R17 measured
// SQ_LDS_BANK_CONFLICT == 0 with this exact read pattern; R13's broken
// (r&3) swizzle cost 2.01e8 conflicts ~ 300us of port cycles).
// 128x256 tile, 8 waves (2Mx4N, 64x64 out, acc[2][2]=64 AGPR -> VGPR~60,
// no spill), BK=64, dbuf 48KB static LDS, DMA prefetch one full tile
// ahead, mfma_scale_f32_32x32x64_f8f6f4, pre-swizzled DMA source
// (both-sides rule), XCD-aware block swizzle.

typedef int i32x4 __attribute__((ext_vector_type(4)));
typedef int i32x8 __attribute__((ext_vector_type(8)));
typedef float f32x16 __attribute__((ext_vector_type(16)));

#define BM 128
#define BN 256
#define BK 64

// clip to +-448, scale (1 or 64), RNE-encode 8 f32 -> 8 e4m3 bytes.
__global__ __launch_bounds__(256) void quant8(
    const float4* __restrict__ in, int2* __restrict__ out, int n8, float scale) {
    int i = blockIdx.x * blockDim.x + threadIdx.x;
    if (i >= n8) return;
    float4 a = in[i * 2];
    float4 b = in[i * 2 + 1];
    float c0 = fminf(fmaxf(a.x, -448.f), 448.f) * scale;
    float c1 = fminf(fmaxf(a.y, -448.f), 448.f) * scale;
    float c2 = fminf(fmaxf(a.z, -448.f), 448.f) * scale;
    float c3 = fminf(fmaxf(a.w, -448.f), 448.f) * scale;
    float c4 = fminf(fmaxf(b.x, -448.f), 448.f) * scale;
    float c5 = fminf(fmaxf(b.y, -448.f), 448.f) * scale;
    float c6 = fminf(fmaxf(b.z, -448.f), 448.f) * scale;
    float c7 = fminf(fmaxf(b.w, -448.f), 448.f) * scale;
    int lo = __builtin_amdgcn_cvt_pk_fp8_f32(c0, c1, 0, false);
    lo = __builtin_amdgcn_cvt_pk_fp8_f32(c2, c3, lo, true);
    int hi = __builtin_amdgcn_cvt_pk_fp8_f32(c4, c5, 0, false);
    hi = __builtin_amdgcn_cvt_pk_fp8_f32(c6, c7, hi, true);
    out[i] = make_int2(lo, hi);
}

__device__ __forceinline__ void gload_lds16(const void* g, void* l) {
    __builtin_amdgcn_global_load_lds(
        (const __attribute__((address_space(1))) void*)g,
        (__attribute__((address_space(3))) void*)l,
        16, 0, 0);
}

// 64B-row tile, slot swizzle q(r) = (r ^ (r>>2)) & 3 (R17: zero conflicts).
// LDS[r][slot s] holds logical slot s ^ q(r). Lane reads 32B = logical
// slots {2*g2, 2*g2+1} of `row`.
__device__ __forceinline__ i32x8 frag64(const unsigned char* base, int row, int g2) {
    const int q = (row ^ (row >> 2)) & 3;
    const unsigned char* p = base + (row << 6);
    i32x4 lo = *(const i32x4*)(p + ((((g2 << 1))     ^ q) << 4));
    i32x4 hi = *(const i32x4*)(p + ((((g2 << 1) | 1) ^ q) << 4));
    i32x8 r;
    r[0] = lo[0]; r[1] = lo[1]; r[2] = lo[2]; r[3] = lo[3];
    r[4] = hi[0]; r[5] = hi[1]; r[6] = hi[2]; r[7] = hi[3];
    return r;
}

// A: Xq8 [M][K] e4m3, B: Wq8 [N][K] e4m3 (pre-scaled by 2^6), C: [M][N] f32
__global__ __launch_bounds__(512, 2) void gemm_fp8(
    const unsigned char* __restrict__ A, const unsigned char* __restrict__ B,
    const float* __restrict__ bias, float* __restrict__ C,
    int M, int N, int K) {
    // buf0: A [0,8K) B [8K,24K); buf1: A [24K,32K) B [32K,48K)
    __shared__ unsigned char lds[49152];

    const int tid = threadIdx.x;
    const int lane = tid & 63;
    const int wave = tid >> 6;
    const int wr = wave >> 2;   // 0..1 -> 64 A-rows each
    const int wc = wave & 3;    // 0..3 -> 64 B-cols each

    // XCD-aware bijective block swizzle (nwg % 8 == 0)
    const int nwg = gridDim.x;
    const int per = nwg >> 3;
    const int bid = blockIdx.x;
    const int wg = (bid & 7) * per + (bid >> 3);
    const int mtiles = M / BM;
    const int bm = wg % mtiles;
    const int bn = wg / mtiles;

    const int arow0 = bm * BM, bcol0 = bn * BN;
    const int NT = K / BK;  // 64

    const int rl = lane & 31;    // fragment row-within-32 (A row / B col)
    const int g2 = lane >> 5;    // k-half selector (32B each)

    const unsigned char* const Ag = A + (size_t)arow0 * K;
    const unsigned char* const Bg = B + (size_t)bcol0 * K;

    // staging: thread t -> row t>>2 within a 128-row chunk, LDS slot t&3
    // (dest linear, DMA constraint); source col carries the inverse
    // swizzle: logical slot = (t&3) ^ q(row). q is invariant under
    // row += c*128 (since (c*128)&3 == 0 and ((c*128)>>2)&3 == 0 mod 4
    // for c*32 ≡ 0 mod 4), so one sq works for all chunks.
    const int srow = tid >> 2;                          // 0..127
    const int sq = (srow ^ (srow >> 2)) & 3;
    const int ssrc = (((tid & 3) ^ sq) << 4);           // byte col in row
    const int sdst = tid * 16;

    auto stage = [&](unsigned char* Lp, int kt) {
        // A: 8KB = 128 rows x 64B = 1 instr/thread
        gload_lds16(Ag + (size_t)srow * K + kt + ssrc, Lp + sdst);
        // B: 16KB = 256 rows = 2 chunks of 128 rows
#pragma unroll
        for (int c = 0; c < 2; ++c)
            gload_lds16(Bg + (size_t)(c * 128 + srow) * K + kt + ssrc,
                        Lp + 8192 + c * 8192 + sdst);
    };

    f32x16 acc[2][2] = {};

    // ---- prologue: tile 0 -> buf0
    stage(lds, 0);
    __syncthreads();  // implicit vmcnt(0): tile 0 landed

    for (int t = 0; t < NT; ++t) {
        const int cur = t & 1;
        const unsigned char* Ab = lds + cur * 24576;
        const unsigned char* Bb = Ab + 8192;
        unsigned char* Anx = lds + (cur ^ 1) * 24576;

        // issue next tile's DMAs first: full tile of latency cover
        if (t + 1 < NT) stage(Anx, (t + 1) * BK);

        i32x8 bf0 = frag64(Bb, wc * 64 + rl, g2);
        i32x8 bf1 = frag64(Bb, wc * 64 + 32 + rl, g2);
        i32x8 af0 = frag64(Ab, wr * 64 + rl, g2);
        i32x8 af1 = frag64(Ab, wr * 64 + 32 + rl, g2);

        acc[0][0] = __builtin_amdgcn_mfma_scale_f32_32x32x64_f8f6f4(
            af0, bf0, acc[0][0], 0, 0, 0, 0x7F7F7F7F, 0, 0x79797979);
        acc[0][1] = __builtin_amdgcn_mfma_scale_f32_32x32x64_f8f6f4(
            af0, bf1, acc[0][1], 0, 0, 0, 0x7F7F7F7F, 0, 0x79797979);
        acc[1][0] = __builtin_amdgcn_mfma_scale_f32_32x32x64_f8f6f4(
            af1, bf0, acc[1][0], 0, 0, 0, 0x7F7F7F7F, 0, 0x79797979);
        acc[1][1] = __builtin_amdgcn_mfma_scale_f32_32x32x64_f8f6f4(
            af1, bf1, acc[1][1], 0, 0, 0, 0x7F7F7F7F, 0, 0x79797979);

        // one sync/tile: DMAs issued ~full tile ago have landed; publishes
        // the next buffer and protects the one just consumed.
        __syncthreads();
    }

    // epilogue: 32x32 C/D: col = lane&31, row = (reg&3)+8*(reg>>2)+4*(lane>>5)
#pragma unroll
    for (int n = 0; n < 2; ++n) {
        int col = bcol0 + wc * 64 + n * 32 + rl;
        float bv = bias[col];
#pragma unroll
        for (int m = 0; m < 2; ++m) {
            int rowb = arow0 + wr * 64 + m * 32 + g2 * 4;
#pragma unroll
            for (int reg = 0; reg < 16; ++reg) {
                int row = rowb + (reg & 3) + 8 * (reg >> 2);
                C[(size_t)row * N + col] = acc[m][n][reg] + bv;
            }
        }
    }
}

extern "C" void kernel_launch(void* const* d_in, const int* in_sizes, int n_in,
                              void* d_out, int out_size, void* d_ws, size_t ws_size,
                              hipStream_t stream) {
    const float* x = (const float*)d_in[0];     // [M,K]
    const float* w = (const float*)d_in[1];     // [N,K]
    const float* bias = (const float*)d_in[2];  // [N]
    float* out = (float*)d_out;

    const int N = in_sizes[2];                 // 16384
    const int K = in_sizes[1] / N;             // 4096
    const int M = in_sizes[0] / K;             // 8192

    unsigned char* xq = (unsigned char*)d_ws;          // M*K = 33.5 MB
    unsigned char* wq = xq + (size_t)M * K;            // N*K = 67 MB

    int nx8 = M * K / 8;
    int nw8 = N * K / 8;
    quant8<<<(nx8 + 255) / 256, 256, 0, stream>>>(
        (const float4*)x, (int2*)xq, nx8, 1.0f);
    quant8<<<(nw8 + 255) / 256, 256, 0, stream>>>(
        (const float4*)w, (int2*)wq, nw8, 64.0f);

    int nwg = (M / BM) * (N / BN);  // 64*64 = 4096, %8==0
    gemm_fp8<<<nwg, 512, 0, stream>>>(
        xq, wq, bias, out, M, N, K);
}